// Round 3
// baseline (173.040 us; speedup 1.0000x reference)
//
#include <hip/hip_runtime.h>
#include <hip/hip_cooperative_groups.h>

namespace cg = cooperative_groups;

#define BB   128        // batch
#define TT   4096       // time
#define NSH  257        // shifts -128..+128 -> j = 0..256
#define PAD  128
#define LTOT 4352.0f    // padded length
#define NCH  2          // t-chunks per row
#define TC   2048       // t per chunk
#define PPW  (TC + 256) // pp window floats per chunk

__device__ __forceinline__ float wave_sum(float v) {
    #pragma unroll
    for (int m = 32; m; m >>= 1) v += __shfl_xor(v, m, 64);
    return v;
}

// Single cooperative kernel: phase 1 = per-chunk cross-correlation partials,
// grid sync, phase 2 = block 0 folds partials -> corr -> max -> mean.
extern "C" __global__ __launch_bounds__(1024, 4)
void k_fused(const float* __restrict__ preds, const float* __restrict__ labels,
             float* __restrict__ cov_ws, float* __restrict__ stats_ws,
             float* __restrict__ out) {
    __shared__ float pp_s[PPW];    // P[t0 + v], P[x] = preds[x-128] zero-padded
    __shared__ float lab_s[TC];
    __shared__ float cov_s[NSH];
    __shared__ float st_s[4];
    __shared__ float part[16];

    const int bid = blockIdx.x;    // 256 blocks
    const int b   = bid >> 1;      // row
    const int c   = bid & 1;       // chunk
    const int t0  = c * TC;
    const int tid = threadIdx.x;

    const float* pr = preds  + b * TT;
    const float* lr = labels + b * TT;

    // ---- stage (coalesced) ----
    #pragma unroll
    for (int v = tid; v < PPW; v += 1024) {
        int idx = t0 + v - PAD;
        pp_s[v] = (idx >= 0 && idx < TT) ? pr[idx] : 0.0f;
    }
    lab_s[tid]        = lr[t0 + tid];
    lab_s[tid + 1024] = lr[t0 + tid + 1024];
    if (tid < NSH) cov_s[tid] = 0.0f;
    if (tid < 4)   st_s[tid]  = 0.0f;
    __syncthreads();

    // ---- main: lane = 4 consecutive shifts (j = 4l..4l+3), wave = 128-t subchunk ----
    const int l    = tid & 63;
    const int wv   = tid >> 6;              // 16 waves
    const int tq0  = wv * (TC / 16);        // 128 t per wave
    const int boff = 256 - 4 * l;

    float4 prev = *reinterpret_cast<const float4*>(&pp_s[tq0 + boff - 4]);
    float a0 = 0.f, a1 = 0.f, a2 = 0.f, a3 = 0.f;

    #pragma unroll 8
    for (int tq = tq0; tq < tq0 + TC / 16; tq += 4) {   // 32 iters
        const float4 lab = *reinterpret_cast<const float4*>(&lab_s[tq]);        // broadcast
        const float4 cur = *reinterpret_cast<const float4*>(&pp_s[tq + boff]);  // conflict-free b128
        a0 += lab.x * cur.x;  a0 += lab.y * cur.y;  a0 += lab.z * cur.z;  a0 += lab.w * cur.w;
        a1 += lab.x * prev.w; a1 += lab.y * cur.x;  a1 += lab.z * cur.y;  a1 += lab.w * cur.z;
        a2 += lab.x * prev.z; a2 += lab.y * prev.w; a2 += lab.z * cur.x;  a2 += lab.w * cur.y;
        a3 += lab.x * prev.y; a3 += lab.y * prev.z; a3 += lab.z * prev.w; a3 += lab.w * cur.x;
        prev = cur;
    }
    atomicAdd(&cov_s[4 * l + 0], a0);
    atomicAdd(&cov_s[4 * l + 1], a1);
    atomicAdd(&cov_s[4 * l + 2], a2);
    atomicAdd(&cov_s[4 * l + 3], a3);

    // ---- shift j=256: sum labels[t]*P[t] (two elems per thread) ----
    {
        float e = lab_s[tid] * pp_s[tid] + lab_s[tid + 1024] * pp_s[tid + 1024];
        e = wave_sum(e);
        if (l == 0) atomicAdd(&cov_s[256], e);
    }

    // ---- per-chunk stats (two elems per thread) ----
    {
        float p0 = pp_s[tid + PAD], p1 = pp_s[tid + 1024 + PAD];
        float l0 = lab_s[tid],      l1 = lab_s[tid + 1024];
        float sp  = wave_sum(p0 + p1);
        float spp = wave_sum(p0 * p0 + p1 * p1);
        float sl  = wave_sum(l0 + l1);
        float sll = wave_sum(l0 * l0 + l1 * l1);
        if (l == 0) {
            atomicAdd(&st_s[0], sp);
            atomicAdd(&st_s[1], spp);
            atomicAdd(&st_s[2], sl);
            atomicAdd(&st_s[3], sll);
        }
    }

    __syncthreads();
    if (tid < NSH) cov_ws[bid * NSH + tid] = cov_s[tid];
    if (tid < 4)   stats_ws[bid * 4 + tid] = st_s[tid];

    __threadfence();
    cg::this_grid().sync();

    // ---- phase 2: block 0 folds chunk partials -> corr -> max -> mean ----
    if (bid != 0) return;

    float sum = 0.f;
    for (int bb = wv; bb < BB; bb += 16) {
        float Sp = 0.f, Spp = 0.f, Sl = 0.f, Sll = 0.f;
        #pragma unroll
        for (int cc = 0; cc < NCH; ++cc) {
            const float* st = stats_ws + (bb * NCH + cc) * 4;
            Sp += st[0]; Spp += st[1]; Sl += st[2]; Sll += st[3];
        }
        float xn2 = Spp - Sp * Sp / LTOT;
        float yn2 = Sll - Sl * Sl / LTOT;
        float inv = rsqrtf(xn2 * yn2);
        float cst = Sp * Sl / LTOT;
        float mx = -1e30f;
        for (int j = l; j < NSH; j += 64) {
            float cv = 0.f;
            #pragma unroll
            for (int cc = 0; cc < NCH; ++cc) cv += cov_ws[(bb * NCH + cc) * NSH + j];
            mx = fmaxf(mx, (cv - cst) * inv);
        }
        #pragma unroll
        for (int m = 32; m; m >>= 1) mx = fmaxf(mx, __shfl_xor(mx, m, 64));
        sum += 1.0f - mx;
    }
    if (l == 0) part[wv] = sum;
    __syncthreads();
    if (tid == 0) {
        float t = 0.f;
        #pragma unroll
        for (int w = 0; w < 16; ++w) t += part[w];
        out[0] = t * (1.0f / BB);
    }
}

extern "C" void kernel_launch(void* const* d_in, const int* in_sizes, int n_in,
                              void* d_out, int out_size, void* d_ws, size_t ws_size,
                              hipStream_t stream) {
    const float* preds  = (const float*)d_in[0];
    const float* labels = (const float*)d_in[1];
    float* out      = (float*)d_out;
    float* cov_ws   = (float*)d_ws;                    // [BB*NCH][NSH]
    float* stats_ws = cov_ws + BB * NCH * NSH;         // [BB*NCH][4]

    void* args[] = {(void*)&preds, (void*)&labels, (void*)&cov_ws,
                    (void*)&stats_ws, (void*)&out};
    hipLaunchCooperativeKernel((const void*)k_fused, dim3(BB * NCH), dim3(1024),
                               args, 0, stream);
}

// Round 4
// 72.327 us; speedup vs baseline: 2.3925x; 2.3925x over previous
//
#include <hip/hip_runtime.h>

#define BB   128        // batch
#define TT   4096       // time
#define NSH  257        // shifts -128..+128 -> j = 0..256
#define PAD  128
#define LTOT 4352.0f    // padded length
#define PPW  (TT + 256) // 4352 pp window floats (full row)

__device__ __forceinline__ float wave_sum(float v) {
    #pragma unroll
    for (int m = 32; m; m >>= 1) v += __shfl_xor(v, m, 64);
    return v;
}

// One dispatch. Blocks 1..128: full-row cross-correlation + in-block finalize,
// publish (loss_b/128) + release-flag. Block 0: spin on flags (agent-scope
// atomics, cross-XCD safe), sum, write out. Flags start as 0xAA poison != 1.
extern "C" __global__ __launch_bounds__(1024)
void k_all(const float* __restrict__ preds, const float* __restrict__ labels,
           float* __restrict__ val_ws, unsigned* __restrict__ flag_ws,
           float* __restrict__ out) {
    const int bid = blockIdx.x;
    const int tid = threadIdx.x;
    const int l   = tid & 63;
    const int wv  = tid >> 6;            // 16 waves

    if (bid == 0) {
        // ---- finalizer: one wave polls 2 flags/lane, then sums ----
        if (wv != 0) return;
        const int r0 = 2 * l, r1 = r0 + 1;
        for (;;) {
            unsigned f0 = __hip_atomic_load(&flag_ws[r0], __ATOMIC_RELAXED, __HIP_MEMORY_SCOPE_AGENT);
            unsigned f1 = __hip_atomic_load(&flag_ws[r1], __ATOMIC_RELAXED, __HIP_MEMORY_SCOPE_AGENT);
            if (__all((f0 == 1u) && (f1 == 1u))) break;
        }
        __builtin_amdgcn_fence(__ATOMIC_ACQUIRE, "agent");
        float v = __hip_atomic_load(&val_ws[r0], __ATOMIC_RELAXED, __HIP_MEMORY_SCOPE_AGENT)
                + __hip_atomic_load(&val_ws[r1], __ATOMIC_RELAXED, __HIP_MEMORY_SCOPE_AGENT);
        v = wave_sum(v);
        if (l == 0) out[0] = v;
        return;
    }

    __shared__ float pp_s[PPW];   // P[v] = preds[v-128], zero-padded
    __shared__ float lab_s[TT];
    __shared__ float cov_s[NSH];
    __shared__ float st_s[4];

    const int b = bid - 1;
    const float* pr = preds  + b * TT;
    const float* lr = labels + b * TT;

    // ---- stage full row (coalesced) ----
    #pragma unroll
    for (int v = tid; v < PPW; v += 1024) {
        int idx = v - PAD;
        pp_s[v] = (idx >= 0 && idx < TT) ? pr[idx] : 0.0f;
    }
    #pragma unroll
    for (int v = tid; v < TT; v += 1024) lab_s[v] = lr[v];
    if (tid < NSH) cov_s[tid] = 0.0f;
    if (tid < 4)   st_s[tid]  = 0.0f;
    __syncthreads();

    // ---- sliding window: lane = 4 consecutive shifts, wave = 256-t slice ----
    const int tq0  = wv * (TT / 16);     // 256 t per wave
    const int boff = 256 - 4 * l;

    float4 prev = *reinterpret_cast<const float4*>(&pp_s[tq0 + boff - 4]);
    float a0 = 0.f, a1 = 0.f, a2 = 0.f, a3 = 0.f;

    #pragma unroll 8
    for (int tq = tq0; tq < tq0 + TT / 16; tq += 4) {   // 64 iters
        const float4 lab = *reinterpret_cast<const float4*>(&lab_s[tq]);        // broadcast
        const float4 cur = *reinterpret_cast<const float4*>(&pp_s[tq + boff]);  // conflict-free b128
        a0 += lab.x * cur.x;  a0 += lab.y * cur.y;  a0 += lab.z * cur.z;  a0 += lab.w * cur.w;
        a1 += lab.x * prev.w; a1 += lab.y * cur.x;  a1 += lab.z * cur.y;  a1 += lab.w * cur.z;
        a2 += lab.x * prev.z; a2 += lab.y * prev.w; a2 += lab.z * cur.x;  a2 += lab.w * cur.y;
        a3 += lab.x * prev.y; a3 += lab.y * prev.z; a3 += lab.z * prev.w; a3 += lab.w * cur.x;
        prev = cur;
    }
    atomicAdd(&cov_s[4 * l + 0], a0);
    atomicAdd(&cov_s[4 * l + 1], a1);
    atomicAdd(&cov_s[4 * l + 2], a2);
    atomicAdd(&cov_s[4 * l + 3], a3);

    // ---- shift j=256 dot + full-row stats (4 elems/thread) ----
    {
        float e = 0.f, sp = 0.f, spp = 0.f, sl = 0.f, sll = 0.f;
        #pragma unroll
        for (int k = 0; k < 4; ++k) {
            int v   = tid + k * 1024;
            float pv = pp_s[v];          // P[v]  (for j=256 term)
            float lv = lab_s[v];
            float pc = pp_s[v + PAD];    // preds[v]
            e  += lv * pv;
            sp += pc; spp += pc * pc;
            sl += lv; sll += lv * lv;
        }
        e  = wave_sum(e);
        sp = wave_sum(sp); spp = wave_sum(spp);
        sl = wave_sum(sl); sll = wave_sum(sll);
        if (l == 0) {
            atomicAdd(&cov_s[256], e);
            atomicAdd(&st_s[0], sp); atomicAdd(&st_s[1], spp);
            atomicAdd(&st_s[2], sl); atomicAdd(&st_s[3], sll);
        }
    }
    __syncthreads();

    // ---- in-block finalize: corr -> max -> publish ----
    if (wv == 0) {
        float Sp = st_s[0], Spp = st_s[1], Sl = st_s[2], Sll = st_s[3];
        float xn2 = Spp - Sp * Sp / LTOT;
        float yn2 = Sll - Sl * Sl / LTOT;
        float inv = rsqrtf(xn2 * yn2);
        float cst = Sp * Sl / LTOT;
        float mx = -1e30f;
        for (int j = l; j < NSH; j += 64)
            mx = fmaxf(mx, (cov_s[j] - cst) * inv);
        #pragma unroll
        for (int m = 32; m; m >>= 1) mx = fmaxf(mx, __shfl_xor(mx, m, 64));
        if (l == 0) {
            __hip_atomic_store(&val_ws[b], (1.0f - mx) * (1.0f / BB),
                               __ATOMIC_RELAXED, __HIP_MEMORY_SCOPE_AGENT);
            __hip_atomic_store(&flag_ws[b], 1u,
                               __ATOMIC_RELEASE, __HIP_MEMORY_SCOPE_AGENT);
        }
    }
}

extern "C" void kernel_launch(void* const* d_in, const int* in_sizes, int n_in,
                              void* d_out, int out_size, void* d_ws, size_t ws_size,
                              hipStream_t stream) {
    const float* preds  = (const float*)d_in[0];
    const float* labels = (const float*)d_in[1];
    float*    out     = (float*)d_out;
    float*    val_ws  = (float*)d_ws;                 // [BB]
    unsigned* flag_ws = (unsigned*)(val_ws + BB);     // [BB], poison 0xAA != 1

    hipLaunchKernelGGL(k_all, dim3(BB + 1), dim3(1024), 0, stream,
                       preds, labels, val_ws, flag_ws, out);
}